// Round 6
// baseline (18821.753 us; speedup 1.0000x reference)
//
#include <hip/hip_runtime.h>

// ---------------- problem constants ----------------
#define NLAYER 64
#define HID    50
#define DIN    60
#define DOUT   50
#define BATCH  32
#define NT     2048
#define NG     200          // 4*HID
#define DEPTH  16           // ring depth (power of two)
#define BS     8            // batch slice per block (BATCH/4)
#define FUEL   (1 << 16)    // spin bound: stall -> wrong results, not a hang
#define KF4    28           // unified K = 112 floats (60 x-part + 50 h-part + 2 pad)

// ---------------- workspace layout ----------------
// prod u32[256] @0 ; cons u32[256] @1024 ; ring @4096 ; y63 after ring
#define RING_OFF   4096
#define SLOT_F     512                                   // 8 rows x 64 floats
#define RING_BYTES ((size_t)256*DEPTH*SLOT_F*4)          // 8 MiB  [(l,q) x 16 slots]
#define Y63_OFF    (RING_OFF + RING_BYTES)

// ---------------- output layout ----------------
#define HS_OFF ((size_t)BATCH*DOUT*NT)                   // 3,276,800
#define CS_OFF (HS_OFF + (size_t)NLAYER*BATCH*HID)       // +102,400

typedef float f4 __attribute__((ext_vector_type(4)));
typedef unsigned long long u64;

// agent-scope (cross-XCD coherent) relaxed atomics — compiler-tracked
#define AL(p)   __hip_atomic_load((p),  __ATOMIC_RELAXED, __HIP_MEMORY_SCOPE_AGENT)
#define AS(p,v) __hip_atomic_store((p), (v), __ATOMIC_RELAXED, __HIP_MEMORY_SCOPE_AGENT)

__device__ __forceinline__ float sigf(float v)  { return 1.f / (1.f + __expf(-v)); }
__device__ __forceinline__ float tanhx(float v) { return 2.f / (1.f + __expf(-2.f*v)) - 1.f; }

// =====================================================================
// Persistent pipelined LSTM: 256 blocks = 64 layers x 4 batch-quarters.
// Weights in LDS [k4][row] (lane-consecutive b128, conflict-free).
// x/h in LDS transposed [k4][b]: GEMM reads them wave-uniform (broadcast).
// Nothing register-resident across the t-loop -> no spill battles.
// Depth-2 prefetch + deferred ring stores hide LLC handoff latency.
// =====================================================================
__global__ __launch_bounds__(256, 1) void lstm_pipe(
    const float* __restrict__ x,   const float* __restrict__ hn,
    const float* __restrict__ cn,  const float* __restrict__ Wih0,
    const float* __restrict__ Wih, const float* __restrict__ Whh,
    const float* __restrict__ bih, const float* __restrict__ bhh,
    unsigned* prod, unsigned* cons, float* ring, float* y63, float* out)
{
  __shared__ f4 w4[KF4*NG];        // 89.6 KB  weights [k4][row r]
  __shared__ f4 xh4[KF4*8];        //  3.5 KB  x(t)|h(t-1) [k4][b]
  __shared__ float g_lds[8*NG];    //  6.4 KB  gates [b][row]
  float* xh_f = (float*)xh4;

  const int tid  = threadIdx.x;
  const int bid  = blockIdx.x;
  const int xcd = bid & 7, jj = bid >> 3;        // layer->XCD grouping (perf only)
  const int l = xcd*8 + (jj >> 2);
  const int q = jj & 3;
  const int r  = tid;                            // gate row (active r<200)
  const int rw = (r < NG) ? r : NG-1;            // clamped for safe LDS reads
  const int KXx = (l == 0) ? DIN : HID;          // real x-part length

  // ---------- prologue: bias + cell state ----------
  float bias_r = 0.f, c0 = 0.f, c1 = 0.f;
  if (r < NG) {
    bias_r = bih[l*NG + r] + bhh[l*NG + r];
    const int u1 = tid, u2 = tid + 200;          // cell ids (b*50+j)
    c0 = cn[((size_t)l*BATCH + q*BS + u1/HID)*HID + u1%HID];
    c1 = cn[((size_t)l*BATCH + q*BS + u2/HID)*HID + u2%HID];
  }

  // ---------- prologue: weights -> LDS (one-time) ----------
  if (r < NG) {
    const float* wx = (l == 0) ? (Wih0 + r*DIN)
                               : (Wih + ((size_t)(l-1)*NG + r)*HID);
    const float* wh = Whh + ((size_t)l*NG + r)*HID;
#pragma unroll
    for (int k4 = 0; k4 < 15; ++k4) {            // x-part: k = 0..59
      f4 v;
#pragma unroll
      for (int j = 0; j < 4; ++j) { const int k = 4*k4 + j; v[j] = (k < KXx) ? wx[k] : 0.f; }
      w4[k4*NG + r] = v;
    }
#pragma unroll
    for (int k4 = 15; k4 < KF4; ++k4) {          // h-part: k = 60..111 (pads 0)
      f4 v;
#pragma unroll
      for (int j = 0; j < 4; ++j) { const int kh = 4*k4 + j - 60; v[j] = (kh < HID) ? wh[kh] : 0.f; }
      w4[k4*NG + r] = v;
    }
  }

  // zero xh (pads must be 0), then scatter h(-1)
  for (int idx = tid; idx < KF4*32; idx += 256) xh_f[idx] = 0.f;
  __syncthreads();
  if (tid < NG) {
#pragma unroll
    for (int half = 0; half < 2; ++half) {
      const int u = tid + half*NG, b = u / HID, j = u % HID, k = 60 + j;
      xh_f[(k >> 2)*32 + b*4 + (k & 3)] = hn[((size_t)l*BATCH + q*BS + b)*HID + j];
    }
  }

  const unsigned* prod_in   = prod + ((l-1)*4 + q);   // deref only if l>0
  unsigned*       prod_out  = prod + (l*4 + q);
  unsigned*       cons_self = cons + (l*4 + q);
  const unsigned* cons_next = cons + ((l+1)*4 + q);   // deref only if l<63

  float*       ring_out = ring + ((size_t)(l*4 + q))*DEPTH*SLOT_F;
  const float* ring_in  = ring + ((size_t)((l-1)*4 + q))*DEPTH*SLOT_F;

  const int e0 = 2*tid, e1 = e0 + 1;
  const int d0_ = e0 & 63, d1_ = d0_ + 1, eb = e0 >> 6;   // (batch row, k-slot) pair

  // ---------- prologue: x(0) -> xh ; fx = x(1) ----------
  float fx0 = 0.f, fx1 = 0.f;
  if (l == 0) {
    if (d0_ < DIN) xh_f[(d0_>>2)*32 + eb*4 + (d0_&3)] = x[((size_t)(q*BS + eb)*DIN + d0_)*NT + 0];
    if (d1_ < DIN) xh_f[(d1_>>2)*32 + eb*4 + (d1_&3)] = x[((size_t)(q*BS + eb)*DIN + d1_)*NT + 0];
    fx0 = (d0_ < DIN) ? x[((size_t)(q*BS + eb)*DIN + d0_)*NT + 1] : 0.f;
    fx1 = (d1_ < DIN) ? x[((size_t)(q*BS + eb)*DIN + d1_)*NT + 1] : 0.f;
  } else {
    const u64* rin64 = (const u64*)ring_in;
    int fuel = FUEL;
    while (AL(prod_in) < 1u && --fuel) __builtin_amdgcn_s_sleep(4);
    u64 v0 = AL(rin64 + tid);
    if (d0_ < HID) xh_f[(d0_>>2)*32 + eb*4 + (d0_&3)] = __uint_as_float((unsigned)v0);
    if (d1_ < HID) xh_f[(d1_>>2)*32 + eb*4 + (d1_&3)] = __uint_as_float((unsigned)(v0 >> 32));
    fuel = FUEL;
    while (AL(prod_in) < 2u && --fuel) __builtin_amdgcn_s_sleep(4);
    u64 v1 = AL(rin64 + SLOT_F/2 + tid);
    fx0 = __uint_as_float((unsigned)v1);
    fx1 = __uint_as_float((unsigned)(v1 >> 32));
    if (tid == 0) AS(cons_self, 2u);
  }
  __syncthreads();

  unsigned c_c = 0;                    // last-polled consumer progress (1-step stale)
  float hh0 = 0.f, hh1 = 0.f;          // h(t-1) held for deferred ring store

  for (int t = 0; t < NT; ++t) {
    // C: deferred ring store of h(t-1) (slot (t-1)&15; wrap-reuse guard)
    if (l < 63 && t >= 1) {
      int fuel = FUEL;
      while ((int)c_c < t - 16 && --fuel) {              // rare (rate-matching)
        c_c = AL(cons_next);
        if ((int)c_c < t - 16) __builtin_amdgcn_s_sleep(4);
      }
      if (tid < NG) {
        unsigned* sb = (unsigned*)(ring_out + ((t-1) & (DEPTH-1))*SLOT_F);
        AS(sb + (tid/HID)*64     + tid%HID, __float_as_uint(hh0));
        AS(sb + (tid/HID + 4)*64 + tid%HID, __float_as_uint(hh1));
      }
    }

    // B: issue polls (results used ~2kcy later -> LLC latency hidden by GEMM)
    unsigned p_c2 = 0, c_c2 = c_c;
    if (l > 0 && t + 2 < NT) p_c2 = AL(prod_in);
    if (l < 63)              c_c2 = AL(cons_next);

    // D: GEMM  gates[b][r] = bias + W.[x;h]
    //    w: lane-consecutive b128 (conflict-free); xh: wave-uniform (broadcast)
    float acc[8];
#pragma unroll
    for (int b = 0; b < 8; ++b) acc[b] = bias_r;
#pragma unroll 4
    for (int k4 = 0; k4 < KF4; ++k4) {
      const f4 w = w4[k4*NG + rw];
#pragma unroll
      for (int b = 0; b < 8; ++b) {
        const f4 xv = xh4[k4*8 + b];
        acc[b] = fmaf(xv[0], w[0], acc[b]);
        acc[b] = fmaf(xv[1], w[1], acc[b]);
        acc[b] = fmaf(xv[2], w[2], acc[b]);
        acc[b] = fmaf(xv[3], w[3], acc[b]);
      }
    }
    if (r < NG) {
#pragma unroll
      for (int b = 0; b < 8; ++b) g_lds[b*NG + r] = acc[b];
    }
    __syncthreads();   // E: gates visible; drains C-stores + B-polls

    // F: xh x-part <- fx (= x(t+1)); pads untouched (stay 0)
    if (t + 1 < NT) {
      if (d0_ < KXx) xh_f[(d0_>>2)*32 + eb*4 + (d0_&3)] = fx0;
      if (d1_ < KXx) xh_f[(d1_>>2)*32 + eb*4 + (d1_&3)] = fx1;
    }

    // G: publish progress (h(0..t-1) at LLC since E drained; x(t+1) extracted)
    if (tid == 0) {
      if (l < 63 && t >= 1) AS(prod_out, (unsigned)t);
      if (l > 0)            AS(cons_self, (unsigned)(t + 2));
    }

    // H: prefetch x(t+2) into fx (used at next F)
    if (t + 2 < NT) {
      if (l == 0) {
        fx0 = (d0_ < DIN) ? x[((size_t)(q*BS + eb)*DIN + d0_)*NT + (t+2)] : 0.f;
        fx1 = (d1_ < DIN) ? x[((size_t)(q*BS + eb)*DIN + d1_)*NT + (t+2)] : 0.f;
      } else {
        int fuel = FUEL;
        while (p_c2 < (unsigned)(t + 3) && --fuel) {     // rare (rate-matching)
          p_c2 = AL(prod_in);
          if (p_c2 < (unsigned)(t + 3)) __builtin_amdgcn_s_sleep(4);
        }
        const u64* lb = (const u64*)(ring_in + ((t+2) & (DEPTH-1))*SLOT_F);
        u64 v = AL(lb + tid);
        fx0 = __uint_as_float((unsigned)v);
        fx1 = __uint_as_float((unsigned)(v >> 32));
      }
    }

    // I: elementwise LSTM update (2 cells/thread, c in regs); h -> xh h-part
    if (tid < NG) {
#pragma unroll
      for (int half = 0; half < 2; ++half) {
        const int u = tid + half*200;
        const int b = u / HID, j = u % HID, k = 60 + j;
        const float cprev = half ? c1 : c0;
        const float gi = g_lds[b*NG +            j];
        const float gf = g_lds[b*NG +  50 +      j];
        const float gg = g_lds[b*NG + 100 +      j];
        const float go = g_lds[b*NG + 150 +      j];
        const float cc = sigf(gf)*cprev + sigf(gi)*tanhx(gg);
        const float hh = sigf(go)*tanhx(cc);
        if (half) { c1 = cc; hh1 = hh; } else { c0 = cc; hh0 = hh; }
        xh_f[(k >> 2)*32 + b*4 + (k & 3)] = hh;
        const int bg = q*BS + b;
        if (l == 63)
          y63[((size_t)t*BATCH + bg)*HID + j] = hh;
        if (t == NT-1) {
          out[HS_OFF + (size_t)l*BATCH*HID + bg*HID + j] = hh;
          out[CS_OFF + (size_t)l*BATCH*HID + bg*HID + j] = cc;
        }
      }
    }
    c_c = c_c2;
    __syncthreads();   // J: xh(t+1) complete; g_lds reusable
  }

  // epilogue: ship h(NT-1) to the ring and publish completion
  if (l < 63) {
    int fuel = FUEL;
    while ((int)c_c < NT - 16 && --fuel) {
      c_c = AL(cons_next);
      if ((int)c_c < NT - 16) __builtin_amdgcn_s_sleep(4);
    }
    if (tid < NG) {
      unsigned* sb = (unsigned*)(ring_out + ((NT-1) & (DEPTH-1))*SLOT_F);
      AS(sb + (tid/HID)*64     + tid%HID, __float_as_uint(hh0));
      AS(sb + (tid/HID + 4)*64 + tid%HID, __float_as_uint(hh1));
    }
    __syncthreads();   // drain stores before publishing
    if (tid == 0) AS(prod_out, (unsigned)NT);
  }
}

// =====================================================================
// FC head: out[b][d][t] = sigmoid(y63[t][b][:] . fc_w[d][:] + fc_b[d])
// =====================================================================
__global__ __launch_bounds__(320, 1) void fc_kernel(
    const float* __restrict__ y63, const float* __restrict__ fcw,
    const float* __restrict__ fcb, float* __restrict__ out)
{
  __shared__ float y_lds[64*52];
  __shared__ float w_lds[50*52];
  __shared__ float b_lds[50];
  const int tid = threadIdx.x;
  const int b  = blockIdx.x >> 5;
  const int t0 = (blockIdx.x & 31) * 64;
  for (int idx = tid; idx < 64*52; idx += 320) {
    const int rr = idx / 52, j = idx % 52;
    y_lds[idx] = (j < HID) ? y63[((size_t)(t0 + rr)*BATCH + b)*HID + j] : 0.f;
  }
  for (int idx = tid; idx < 50*52; idx += 320) {
    const int rr = idx / 52, j = idx % 52;
    w_lds[idx] = (j < HID) ? fcw[rr*HID + j] : 0.f;
  }
  if (tid < 50) b_lds[tid] = fcb[tid];
  __syncthreads();
  const int toff = tid & 63, dg = tid >> 6;   // dg in [0,5)
  for (int d = dg; d < DOUT; d += 5) {
    float acc = b_lds[d];
#pragma unroll
    for (int j4 = 0; j4 < 13; ++j4) {
      f4 yv = *(const f4*)&y_lds[toff*52 + j4*4];
      f4 wv = *(const f4*)&w_lds[d*52 + j4*4];
#pragma unroll
      for (int j = 0; j < 4; ++j) acc = fmaf(yv[j], wv[j], acc);
    }
    out[((size_t)b*DOUT + d)*NT + t0 + toff] = 1.f / (1.f + __expf(-acc));
  }
}

extern "C" void kernel_launch(void* const* d_in, const int* in_sizes, int n_in,
                              void* d_out, int out_size, void* d_ws, size_t ws_size,
                              hipStream_t stream)
{
  const float* x    = (const float*)d_in[0];
  const float* hn   = (const float*)d_in[1];
  const float* cn   = (const float*)d_in[2];
  const float* Wih0 = (const float*)d_in[3];
  const float* Wih  = (const float*)d_in[4];
  const float* Whh  = (const float*)d_in[5];
  const float* bih  = (const float*)d_in[6];
  const float* bhh  = (const float*)d_in[7];
  const float* fcw  = (const float*)d_in[8];
  const float* fcb  = (const float*)d_in[9];
  float* out = (float*)d_out;

  unsigned* prod = (unsigned*)d_ws;
  unsigned* cons = (unsigned*)((char*)d_ws + 1024);
  float*    ring = (float*)((char*)d_ws + RING_OFF);
  float*    y63  = (float*)((char*)d_ws + Y63_OFF);
  (void)in_sizes; (void)n_in; (void)out_size; (void)ws_size;

  // prod/cons counters must start at zero (ws is re-poisoned 0xAA each call)
  hipMemsetAsync(d_ws, 0, 4096, stream);

  hipLaunchKernelGGL(lstm_pipe, dim3(256), dim3(256), 0, stream,
                     x, hn, cn, Wih0, Wih, Whh, bih, bhh,
                     prod, cons, ring, y63, out);
  hipLaunchKernelGGL(fc_kernel, dim3(1024), dim3(320), 0, stream, y63, fcw, fcb, out);
}

// Round 7
// 17930.623 us; speedup vs baseline: 1.0497x; 1.0497x over previous
//
#include <hip/hip_runtime.h>

// ---------------- problem constants ----------------
#define NLAYER 64
#define HID    50
#define DIN    60
#define DOUT   50
#define BATCH  32
#define NT     2048
#define NG     200          // 4*HID
#define DEPTH  16           // ring depth (power of two)
#define BS     8            // batch slice per block (BATCH/4)
#define FUEL   (1 << 16)    // spin bound: stall -> wrong results, not a hang
#define KF4    28           // k4 chunks: 15 x-part (60) + 13 h-part (52)

// ---------------- workspace layout ----------------
// prod u32[256] @0 ; cons u32[256] @1024 ; ring @4096 ; y63 after ring
#define RING_OFF   4096
#define SLOT_F     512                                   // 8 rows x 64 floats
#define RING_BYTES ((size_t)256*DEPTH*SLOT_F*4)          // 8 MiB
#define Y63_OFF    (RING_OFF + RING_BYTES)

// ---------------- output layout ----------------
#define HS_OFF ((size_t)BATCH*DOUT*NT)                   // 3,276,800
#define CS_OFF (HS_OFF + (size_t)NLAYER*BATCH*HID)       // +102,400

typedef float f4 __attribute__((ext_vector_type(4)));
typedef float f2 __attribute__((ext_vector_type(2)));
typedef unsigned long long u64;

// agent-scope (cross-XCD coherent) relaxed atomics — compiler-tracked
#define AL(p)   __hip_atomic_load((p),  __ATOMIC_RELAXED, __HIP_MEMORY_SCOPE_AGENT)
#define AS(p,v) __hip_atomic_store((p), (v), __ATOMIC_RELAXED, __HIP_MEMORY_SCOPE_AGENT)

__device__ __forceinline__ float sigf(float v)  { return 1.f / (1.f + __expf(-v)); }
__device__ __forceinline__ float tanhx(float v) { return 2.f / (1.f + __expf(-2.f*v)) - 1.f; }
__device__ __forceinline__ u64 pack2(float a, float b) {
  return (u64)__float_as_uint(a) | ((u64)__float_as_uint(b) << 32);
}

// GEMM slice over k4 range [K0,K1): weights lane-distinct from LDS,
// xh broadcast from wave-distributed regs via v_readlane (per-SIMD pipe).
template<int K0, int K1>
__device__ __forceinline__ void gemm_part(const f4* w4, int rw,
                                          f4 X0, f4 X1, f4 X2, f4 X3,
                                          float* acc) {
#pragma unroll
  for (int k4 = K0; k4 < K1; ++k4) {
    const f4 w = w4[k4*NG + rw];
#pragma unroll
    for (int b = 0; b < 8; ++b) {
      const int c = k4*8 + b;                 // chunk id (compile-time)
#pragma unroll
      for (int j = 0; j < 4; ++j) {
        const float s = (c < 64) ? X0[j] : (c < 128) ? X1[j]
                       : (c < 192) ? X2[j] : X3[j];
        const float v = __uint_as_float(
            __builtin_amdgcn_readlane(__float_as_uint(s), c & 63));
        acc[b] = fmaf(v, w[j], acc[b]);
      }
    }
  }
}

// =====================================================================
// Persistent pipelined LSTM: 256 blocks = 64 layers x 4 batch-quarters.
// Weights in LDS [k4][row] (lane-distinct b128, ~112 instr/CU/step).
// xh chunk-linear in LDS; bulk-read 4 b128/wave -> readlane broadcast.
// Elementwise pair-mapped (b, 2j): all writes are aligned b64.
// =====================================================================
__global__ __launch_bounds__(256, 1) void lstm_pipe(
    const float* __restrict__ x,   const float* __restrict__ hn,
    const float* __restrict__ cn,  const float* __restrict__ Wih0,
    const float* __restrict__ Wih, const float* __restrict__ Whh,
    const float* __restrict__ bih, const float* __restrict__ bhh,
    unsigned* prod, unsigned* cons, float* ring, float* y63, float* out)
{
  __shared__ f4 w4[KF4*NG];        // 89.6 KB  weights [k4][row r]
  __shared__ f4 xh4c[256];         //  4.0 KB  xh chunks: c = k4*8 + b (pads 0)
  __shared__ float g_lds[8*NG];    //  6.4 KB  gates [b][row]
  float* xh_f = (float*)xh4c;

  const int tid  = threadIdx.x;
  const int lane = tid & 63;
  const int bid  = blockIdx.x;
  const int xcd = bid & 7, jj = bid >> 3;        // layer->XCD grouping (perf only)
  const int l = xcd*8 + (jj >> 2);
  const int q = jj & 3;
  const int r  = tid;                            // gate row (active r<200)
  const int rw = (r < NG) ? r : NG-1;            // clamped for safe LDS reads

  // pair ownership: thread -> (batch bw, j-pair jw0,jw0+1)
  bool xw_ok; int bw, jw0;
  if (tid < NG)                    { bw = tid/25;        jw0 = 2*(tid%25);            xw_ok = true; }
  else if (l == 0 && tid < 240)    { const int ix = tid-NG; bw = ix/5; jw0 = 50+2*(ix%5); xw_ok = true; }
  else                             { bw = 0; jw0 = 0; xw_ok = false; }

  // ---------- prologue: bias + cell state ----------
  float bias_r = 0.f, c0 = 0.f, c1 = 0.f;
  if (r < NG) bias_r = bih[l*NG + r] + bhh[l*NG + r];
  if (tid < NG) {
    c0 = cn[((size_t)l*BATCH + q*BS + bw)*HID + jw0];
    c1 = cn[((size_t)l*BATCH + q*BS + bw)*HID + jw0 + 1];
  }

  // ---------- prologue: weights -> LDS (one-time) ----------
  if (r < NG) {
    const int KXx = (l == 0) ? DIN : HID;
    const float* wx = (l == 0) ? (Wih0 + r*DIN)
                               : (Wih + ((size_t)(l-1)*NG + r)*HID);
    const float* wh = Whh + ((size_t)l*NG + r)*HID;
#pragma unroll
    for (int k4 = 0; k4 < 15; ++k4) {            // x-part: k = 0..59
      f4 v;
#pragma unroll
      for (int j = 0; j < 4; ++j) { const int k = 4*k4 + j; v[j] = (k < KXx) ? wx[k] : 0.f; }
      w4[k4*NG + r] = v;
    }
#pragma unroll
    for (int k4 = 15; k4 < KF4; ++k4) {          // h-part: k = 60..111 (pads 0)
      f4 v;
#pragma unroll
      for (int j = 0; j < 4; ++j) { const int kh = 4*k4 + j - 60; v[j] = (kh < HID) ? wh[kh] : 0.f; }
      w4[k4*NG + r] = v;
    }
  }

  // zero xh chunks (pads must stay 0)
  if (tid < 256) xh4c[tid] = (f4){0.f, 0.f, 0.f, 0.f};
  __syncthreads();

  // h(-1) -> xh h-part (pair b64 writes)
  if (tid < NG) {
    const int k = 60 + jw0, ck = (k >> 2)*8 + bw;
    f2 h2 = { hn[((size_t)l*BATCH + q*BS + bw)*HID + jw0],
              hn[((size_t)l*BATCH + q*BS + bw)*HID + jw0 + 1] };
    *(f2*)&xh_f[ck*4 + (k & 3)] = h2;
  }

  const unsigned* prod_in   = prod + ((l-1)*4 + q);   // deref only if l>0
  unsigned*       prod_out  = prod + (l*4 + q);
  unsigned*       cons_self = cons + (l*4 + q);
  const unsigned* cons_next = cons + ((l+1)*4 + q);   // deref only if l<63

  float*       ring_out = ring + ((size_t)(l*4 + q))*DEPTH*SLOT_F;
  const float* ring_in  = ring + ((size_t)((l-1)*4 + q))*DEPTH*SLOT_F;

  // ---------- prologue: x(0) -> xh ; fx = x(1) ----------
  float fx0 = 0.f, fx1 = 0.f;
  if (l == 0) {
    if (xw_ok) {
      const int ck = (jw0 >> 2)*8 + bw;
      f2 v0 = { x[((size_t)(q*BS + bw)*DIN + jw0)*NT + 0],
                x[((size_t)(q*BS + bw)*DIN + jw0 + 1)*NT + 0] };
      *(f2*)&xh_f[ck*4 + (jw0 & 3)] = v0;
      fx0 = x[((size_t)(q*BS + bw)*DIN + jw0)*NT + 1];
      fx1 = x[((size_t)(q*BS + bw)*DIN + jw0 + 1)*NT + 1];
    }
  } else {
    int fuel = FUEL;
    while (AL(prod_in) < 1u && --fuel) __builtin_amdgcn_s_sleep(4);
    if (xw_ok) {
      u64 v = AL((const u64*)(ring_in + bw*64 + jw0));
      const int ck = (jw0 >> 2)*8 + bw;
      *(f2*)&xh_f[ck*4 + (jw0 & 3)] =
          (f2){ __uint_as_float((unsigned)v), __uint_as_float((unsigned)(v >> 32)) };
    }
    fuel = FUEL;
    while (AL(prod_in) < 2u && --fuel) __builtin_amdgcn_s_sleep(4);
    if (xw_ok) {
      u64 v = AL((const u64*)(ring_in + SLOT_F + bw*64 + jw0));
      fx0 = __uint_as_float((unsigned)v);
      fx1 = __uint_as_float((unsigned)(v >> 32));
    }
    if (tid == 0) AS(cons_self, 2u);
  }
  __syncthreads();

  unsigned c_c = 0;                    // last-polled consumer progress
  float hh0 = 0.f, hh1 = 0.f;          // h(t-1) pair for deferred ring store

  for (int t = 0; t < NT; ++t) {
    // A: bulk read xh into regs (4x sequential conflict-free ds_read_b128)
    f4 X0 = xh4c[lane], X1 = xh4c[lane + 64];
    f4 X2 = xh4c[lane + 128], X3 = xh4c[lane + 192];

    // C: deferred ring store of h(t-1) (slot (t-1)&15; wrap-reuse guard)
    if (l < 63 && t >= 1) {
      int fuel = FUEL;
      while ((int)c_c < t - 16 && --fuel) {              // rare (rate-matching)
        c_c = AL(cons_next);
        if ((int)c_c < t - 16) __builtin_amdgcn_s_sleep(4);
      }
      if (tid < NG)
        AS((u64*)(ring_out + ((t-1) & (DEPTH-1))*SLOT_F + bw*64 + jw0),
           pack2(hh0, hh1));
    }

    // B: issue polls (results used much later -> LLC latency hidden by GEMM)
    unsigned p_c2 = 0, c_c2 = c_c;
    if (l > 0 && t + 2 < NT) p_c2 = AL(prod_in);
    if (l < 63)              c_c2 = AL(cons_next);

    // D: GEMM  gates[b][r] = bias + W.[x;h]
    float acc[8];
#pragma unroll
    for (int b = 0; b < 8; ++b) acc[b] = bias_r;
    gemm_part<0,13>(w4, rw, X0, X1, X2, X3, acc);        // x k=0..51
    if (l == 0) gemm_part<13,15>(w4, rw, X0, X1, X2, X3, acc);  // x k=52..59
    gemm_part<15,28>(w4, rw, X0, X1, X2, X3, acc);       // h k=60..111
    if (r < NG) {
#pragma unroll
      for (int b = 0; b < 8; ++b) g_lds[b*NG + r] = acc[b];
    }
    __syncthreads();   // E: gates visible; drains C-stores + B-polls

    // F: xh x-part <- fx (= x(t+1)), aligned b64
    if (xw_ok && t + 1 < NT) {
      const int ck = (jw0 >> 2)*8 + bw;
      *(f2*)&xh_f[ck*4 + (jw0 & 3)] = (f2){fx0, fx1};
    }

    // G: publish progress
    if (tid == 0) {
      if (l < 63 && t >= 1) AS(prod_out, (unsigned)t);
      if (l > 0)            AS(cons_self, (unsigned)(t + 2));
    }

    // H: prefetch x(t+2) into fx
    if (t + 2 < NT) {
      if (l == 0) {
        if (xw_ok) {
          fx0 = x[((size_t)(q*BS + bw)*DIN + jw0)*NT + (t+2)];
          fx1 = x[((size_t)(q*BS + bw)*DIN + jw0 + 1)*NT + (t+2)];
        }
      } else {
        int fuel = FUEL;
        while (p_c2 < (unsigned)(t + 3) && --fuel) {     // rare (rate-matching)
          p_c2 = AL(prod_in);
          if (p_c2 < (unsigned)(t + 3)) __builtin_amdgcn_s_sleep(4);
        }
        if (xw_ok) {
          u64 v = AL((const u64*)(ring_in + ((t+2) & (DEPTH-1))*SLOT_F + bw*64 + jw0));
          fx0 = __uint_as_float((unsigned)v);
          fx1 = __uint_as_float((unsigned)(v >> 32));
        }
      }
    }

    // I: elementwise LSTM update (pair of adjacent cells per thread)
    if (tid < NG) {
      f2 gi = *(f2*)&g_lds[bw*NG +        jw0];
      f2 gf = *(f2*)&g_lds[bw*NG +  50 + jw0];
      f2 gg = *(f2*)&g_lds[bw*NG + 100 + jw0];
      f2 go = *(f2*)&g_lds[bw*NG + 150 + jw0];
      const float cc0 = sigf(gf[0])*c0 + sigf(gi[0])*tanhx(gg[0]);
      const float nh0 = sigf(go[0])*tanhx(cc0);
      const float cc1 = sigf(gf[1])*c1 + sigf(gi[1])*tanhx(gg[1]);
      const float nh1 = sigf(go[1])*tanhx(cc1);
      c0 = cc0; c1 = cc1; hh0 = nh0; hh1 = nh1;
      const int k = 60 + jw0, ck = (k >> 2)*8 + bw;
      *(f2*)&xh_f[ck*4 + (k & 3)] = (f2){nh0, nh1};      // h -> xh (b64)
      const int bg = q*BS + bw;
      if (l == 63)
        *(f2*)&y63[((size_t)t*BATCH + bg)*HID + jw0] = (f2){nh0, nh1};
      if (t == NT-1) {
        *(f2*)&out[HS_OFF + (size_t)l*BATCH*HID + bg*HID + jw0] = (f2){nh0, nh1};
        *(f2*)&out[CS_OFF + (size_t)l*BATCH*HID + bg*HID + jw0] = (f2){cc0, cc1};
      }
    }
    c_c = c_c2;
    __syncthreads();   // J: xh(t+1) complete; g_lds reusable
  }

  // epilogue: ship h(NT-1) to the ring and publish completion
  if (l < 63) {
    int fuel = FUEL;
    while ((int)c_c < NT - 16 && --fuel) {
      c_c = AL(cons_next);
      if ((int)c_c < NT - 16) __builtin_amdgcn_s_sleep(4);
    }
    if (tid < NG)
      AS((u64*)(ring_out + ((NT-1) & (DEPTH-1))*SLOT_F + bw*64 + jw0),
         pack2(hh0, hh1));
    __syncthreads();   // drain stores before publishing
    if (tid == 0) AS(prod_out, (unsigned)NT);
  }
}

// =====================================================================
// FC head: out[b][d][t] = sigmoid(y63[t][b][:] . fc_w[d][:] + fc_b[d])
// =====================================================================
__global__ __launch_bounds__(320, 1) void fc_kernel(
    const float* __restrict__ y63, const float* __restrict__ fcw,
    const float* __restrict__ fcb, float* __restrict__ out)
{
  __shared__ float y_lds[64*52];
  __shared__ float w_lds[50*52];
  __shared__ float b_lds[50];
  const int tid = threadIdx.x;
  const int b  = blockIdx.x >> 5;
  const int t0 = (blockIdx.x & 31) * 64;
  for (int idx = tid; idx < 64*52; idx += 320) {
    const int rr = idx / 52, j = idx % 52;
    y_lds[idx] = (j < HID) ? y63[((size_t)(t0 + rr)*BATCH + b)*HID + j] : 0.f;
  }
  for (int idx = tid; idx < 50*52; idx += 320) {
    const int rr = idx / 52, j = idx % 52;
    w_lds[idx] = (j < HID) ? fcw[rr*HID + j] : 0.f;
  }
  if (tid < 50) b_lds[tid] = fcb[tid];
  __syncthreads();
  const int toff = tid & 63, dg = tid >> 6;   // dg in [0,5)
  for (int d = dg; d < DOUT; d += 5) {
    float acc = b_lds[d];
#pragma unroll
    for (int j4 = 0; j4 < 13; ++j4) {
      f4 yv = *(const f4*)&y_lds[toff*52 + j4*4];
      f4 wv = *(const f4*)&w_lds[d*52 + j4*4];
#pragma unroll
      for (int j = 0; j < 4; ++j) acc = fmaf(yv[j], wv[j], acc);
    }
    out[((size_t)b*DOUT + d)*NT + t0 + toff] = 1.f / (1.f + __expf(-acc));
  }
}

extern "C" void kernel_launch(void* const* d_in, const int* in_sizes, int n_in,
                              void* d_out, int out_size, void* d_ws, size_t ws_size,
                              hipStream_t stream)
{
  const float* x    = (const float*)d_in[0];
  const float* hn   = (const float*)d_in[1];
  const float* cn   = (const float*)d_in[2];
  const float* Wih0 = (const float*)d_in[3];
  const float* Wih  = (const float*)d_in[4];
  const float* Whh  = (const float*)d_in[5];
  const float* bih  = (const float*)d_in[6];
  const float* bhh  = (const float*)d_in[7];
  const float* fcw  = (const float*)d_in[8];
  const float* fcb  = (const float*)d_in[9];
  float* out = (float*)d_out;

  unsigned* prod = (unsigned*)d_ws;
  unsigned* cons = (unsigned*)((char*)d_ws + 1024);
  float*    ring = (float*)((char*)d_ws + RING_OFF);
  float*    y63  = (float*)((char*)d_ws + Y63_OFF);
  (void)in_sizes; (void)n_in; (void)out_size; (void)ws_size;

  // prod/cons counters must start at zero (ws is re-poisoned 0xAA each call)
  hipMemsetAsync(d_ws, 0, 4096, stream);

  hipLaunchKernelGGL(lstm_pipe, dim3(256), dim3(256), 0, stream,
                     x, hn, cn, Wih0, Wih, Whh, bih, bhh,
                     prod, cons, ring, y63, out);
  hipLaunchKernelGGL(fc_kernel, dim3(1024), dim3(320), 0, stream, y63, fcw, fcb, out);
}